// Round 1
// baseline (81.228 us; speedup 1.0000x reference)
//
#include <hip/hip_runtime.h>

#define M_NODES 100000

typedef float  f32x4  __attribute__((ext_vector_type(4)));
typedef short  bf16x8 __attribute__((ext_vector_type(8)));
typedef unsigned short u16x4 __attribute__((ext_vector_type(4)));

__device__ __forceinline__ unsigned short f2bf(float f) {
  union { float f; unsigned int u; } v; v.f = f;
  unsigned int u = v.u;
  return (unsigned short)((u + 0x7FFFu + ((u >> 16) & 1u)) >> 16);  // RNE
}

// ---------------------------------------------------------------------------
// prep: W[256][256] f32 (k-major rows) -> 4 swizzled bf16 k-tile LDS images.
// Image layout (ushort units): kt*16384 + n*64 + (((kl>>3)^(n&7))<<3) + (kl&7)
//   holds bf16(W[kt*64+kl][n]).  (16B slot XOR-swizzle: T2, st_16x32-style.)
// ---------------------------------------------------------------------------
__global__ void prep_w_kernel(const float* __restrict__ W1, const float* __restrict__ W2,
                              unsigned short* __restrict__ R1, unsigned short* __restrict__ R2) {
  int b = blockIdx.x;                     // 128 blocks x 256 threads
  const float* W = (b < 64) ? W1 : W2;
  unsigned short* R = (b < 64) ? R1 : R2;
  int e  = ((b & 63) * 256 + (int)threadIdx.x) * 4;  // [0, 65536)
  int n  = e >> 8;
  int k0 = e & 255;                        // multiple of 4 -> stays in one 16B slot half
  u16x4 h;
  #pragma unroll
  for (int i = 0; i < 4; ++i) h[i] = f2bf(W[(k0 + i) * 256 + n]);
  int kt = k0 >> 6, kl = k0 & 63;
  int off = kt * 16384 + n * 64 + (((kl >> 3) ^ (n & 7)) << 3) + (kl & 7);
  *(u16x4*)(R + off) = h;
}

// ---------------------------------------------------------------------------
// GEMM: C[BM=64 x 256] = A[64 x 256] * W[256 x 256] (+bias, epilogue per PASS)
// 256 threads = 4 waves; wave w owns cols [64w, 64w+64): 4x4 frags of 16x16x32.
// PASS 1: A = X fp32 (reg-stage + cvt + swizzled ds_write), epilogue relu ->
//         pre-swizzled bf16 H tile images in ws.
// PASS 2: A = H images (global_load_lds linear), epilogue +b2 -> f32 out.
// LDS: A dbuf 2x8KB + W dbuf 2x32KB = 80KB -> 2 blocks/CU.
// ---------------------------------------------------------------------------
template <int PASS>
__global__ __launch_bounds__(256, 2)
void cheb_gemm(const float* __restrict__ Af32,          // PASS1: X
               const unsigned short* __restrict__ Aimg, // PASS2: H images
               const unsigned short* __restrict__ Wimg, // W_ready images
               const float* __restrict__ bias,
               unsigned short* __restrict__ Hout,       // PASS1 out
               float* __restrict__ Cout)                // PASS2 out
{
  __shared__ unsigned short lds[40960];   // 80 KB
  unsigned short* Ab0 = lds;              // 4096 ushorts (8KB)
  unsigned short* Ab1 = lds + 4096;
  unsigned short* Wb0 = lds + 8192;       // 16384 ushorts (32KB)
  unsigned short* Wb1 = lds + 24576;

  const int tid  = threadIdx.x;
  const int lane = tid & 63;
  const int w    = tid >> 6;
  const int rb   = blockIdx.x;

  f32x4 acc[4][4] = {};
  f32x4 areg[4];

  // --- staging helpers -----------------------------------------------------
  auto stageW = [&](int kt, unsigned short* dst) {
    const unsigned short* src = Wimg + kt * 16384;
    #pragma unroll
    for (int it = 0; it < 8; ++it) {
      int chunk = it * 4 + w;             // wave-uniform
      __builtin_amdgcn_global_load_lds(
          (const __attribute__((address_space(1))) unsigned int*)(const void*)(src + chunk * 512 + lane * 8),
          (__attribute__((address_space(3))) unsigned int*)(void*)(dst + chunk * 512),
          16, 0, 0);
    }
  };
  auto stageA2 = [&](int kt, unsigned short* dst) {
    const unsigned short* src = Aimg + (size_t)(rb * 4 + kt) * 4096;
    #pragma unroll
    for (int it = 0; it < 2; ++it) {
      int chunk = it * 4 + w;
      __builtin_amdgcn_global_load_lds(
          (const __attribute__((address_space(1))) unsigned int*)(const void*)(src + chunk * 512 + lane * 8),
          (__attribute__((address_space(3))) unsigned int*)(void*)(dst + chunk * 512),
          16, 0, 0);
    }
  };
  auto loadA1 = [&](int kt) {             // issue global f32 loads (latency hidden by compute)
    #pragma unroll
    for (int i = 0; i < 4; ++i) {
      int e = (i * 256 + tid) * 4;
      int r = e >> 6, c = e & 63;
      int grow = rb * 64 + r;
      f32x4 v = {0.f, 0.f, 0.f, 0.f};
      if (grow < M_NODES) v = *(const f32x4*)(Af32 + (size_t)grow * 256 + kt * 64 + c);
      areg[i] = v;
    }
  };
  auto writeA1 = [&](unsigned short* dst) {  // cvt + swizzled ds_write
    #pragma unroll
    for (int i = 0; i < 4; ++i) {
      int e = (i * 256 + tid) * 4;
      int r = e >> 6, c = e & 63;
      u16x4 h;
      #pragma unroll
      for (int j = 0; j < 4; ++j) h[j] = f2bf(areg[i][j]);
      int off = r * 64 + (((c >> 3) ^ (r & 7)) << 3) + (c & 7);
      *(u16x4*)(dst + off) = h;
    }
  };
  auto compute = [&](const unsigned short* A, const unsigned short* B) {
    #pragma unroll
    for (int kk = 0; kk < 2; ++kk) {
      bf16x8 a[4], b[4];
      #pragma unroll
      for (int mi = 0; mi < 4; ++mi) {
        int r = mi * 16 + (lane & 15);
        int slot = (kk * 4 + (lane >> 4)) ^ (r & 7);
        a[mi] = *(const bf16x8*)(A + r * 64 + slot * 8);
      }
      #pragma unroll
      for (int ni = 0; ni < 4; ++ni) {
        int n = w * 64 + ni * 16 + (lane & 15);
        int slot = (kk * 4 + (lane >> 4)) ^ (n & 7);
        b[ni] = *(const bf16x8*)(B + n * 64 + slot * 8);
      }
      #pragma unroll
      for (int mi = 0; mi < 4; ++mi)
        #pragma unroll
        for (int ni = 0; ni < 4; ++ni)
          acc[mi][ni] = __builtin_amdgcn_mfma_f32_16x16x32_bf16(a[mi], b[ni], acc[mi][ni], 0, 0, 0);
    }
  };

  // --- prologue ------------------------------------------------------------
  if (PASS == 1) { loadA1(0); writeA1(Ab0); } else { stageA2(0, Ab0); }
  stageW(0, Wb0);
  __syncthreads();

  // --- K loop (4 steps, fully unrolled: all buffer indices compile-time) ---
  #pragma unroll
  for (int kt = 0; kt < 4; ++kt) {
    unsigned short* Acur = (kt & 1) ? Ab1 : Ab0;
    unsigned short* Anxt = (kt & 1) ? Ab0 : Ab1;
    unsigned short* Wcur = (kt & 1) ? Wb1 : Wb0;
    unsigned short* Wnxt = (kt & 1) ? Wb0 : Wb1;
    if (kt < 3) {
      if (PASS == 1) loadA1(kt + 1); else stageA2(kt + 1, Anxt);
      stageW(kt + 1, Wnxt);
    }
    compute(Acur, Wcur);
    if (PASS == 1 && kt < 3) writeA1(Anxt);
    __syncthreads();
  }

  // --- epilogue ------------------------------------------------------------
  float bn[4];
  #pragma unroll
  for (int ni = 0; ni < 4; ++ni) bn[ni] = bias[w * 64 + ni * 16 + (lane & 15)];

  if (PASS == 1) {
    unsigned short* img = Hout + (size_t)(rb * 4 + w) * 4096;
    #pragma unroll
    for (int mi = 0; mi < 4; ++mi)
      #pragma unroll
      for (int ni = 0; ni < 4; ++ni)
        #pragma unroll
        for (int rg = 0; rg < 4; ++rg) {
          int r = mi * 16 + (lane >> 4) * 4 + rg;
          int k = ni * 16 + (lane & 15);
          float v = acc[mi][ni][rg] + bn[ni];
          v = fmaxf(v, 0.f);
          int off = r * 64 + (((k >> 3) ^ (r & 7)) << 3) + (k & 7);
          img[off] = f2bf(v);
        }
  } else {
    #pragma unroll
    for (int mi = 0; mi < 4; ++mi)
      #pragma unroll
      for (int rg = 0; rg < 4; ++rg) {
        int r = mi * 16 + (lane >> 4) * 4 + rg;
        int grow = rb * 64 + r;
        if (grow < M_NODES) {
          #pragma unroll
          for (int ni = 0; ni < 4; ++ni) {
            int col = w * 64 + ni * 16 + (lane & 15);
            Cout[(size_t)grow * 256 + col] = acc[mi][ni][rg] + bn[ni];
          }
        }
      }
  }
}

// ---------------------------------------------------------------------------
extern "C" void kernel_launch(void* const* d_in, const int* in_sizes, int n_in,
                              void* d_out, int out_size, void* d_ws, size_t ws_size,
                              hipStream_t stream) {
  const float* emb = (const float*)d_in[0];
  const float* W1  = (const float*)d_in[1];
  const float* b1  = (const float*)d_in[2];
  const float* W2  = (const float*)d_in[3];
  const float* b2  = (const float*)d_in[4];
  // d_in[5] = prop_edge_index: unused at ChebConv K=1.
  float* out = (float*)d_out;

  unsigned short* Wr1  = (unsigned short*)d_ws;          // 65536 ushorts (128KB)
  unsigned short* Wr2  = Wr1 + 65536;                    // 128KB
  unsigned short* Himg = Wr2 + 65536;                    // 1563*4*4096 ushorts = 51.2MB

  prep_w_kernel<<<128, 256, 0, stream>>>(W1, W2, Wr1, Wr2);

  const int grid = (M_NODES + 63) / 64;                  // 1563
  cheb_gemm<1><<<grid, 256, 0, stream>>>(emb, nullptr, Wr1, b1, Himg, nullptr);
  cheb_gemm<2><<<grid, 256, 0, stream>>>(nullptr, Himg, Wr2, b2, nullptr, out);
}

// Round 2
// 74.861 us; speedup vs baseline: 1.0850x; 1.0850x over previous
//
#include <hip/hip_runtime.h>

#define M_NODES 100000
#define BM 128
#define NBLK ((M_NODES + BM - 1) / BM)   // 782

typedef float  f32x4  __attribute__((ext_vector_type(4)));
typedef short  bf16x8 __attribute__((ext_vector_type(8)));
typedef unsigned short u16x4 __attribute__((ext_vector_type(4)));

__device__ __forceinline__ unsigned short f2bf(float f) {
  union { float f; unsigned int u; } v; v.f = f;
  unsigned int u = v.u;
  return (unsigned short)((u + 0x7FFFu + ((u >> 16) & 1u)) >> 16);  // RNE
}

// ---------------------------------------------------------------------------
// prep: W[256][256] f32 (k-major rows) -> 4 swizzled bf16 k-tile LDS images.
// Image layout (ushort units): kt*16384 + n*64 + (((kl>>3)^(n&7))<<3) + (kl&7)
//   holds bf16(W[kt*64+kl][n]).
// ---------------------------------------------------------------------------
__global__ void prep_w_kernel(const float* __restrict__ W1, const float* __restrict__ W2,
                              unsigned short* __restrict__ R1, unsigned short* __restrict__ R2) {
  int b = blockIdx.x;                     // 128 blocks x 256 threads
  const float* W = (b < 64) ? W1 : W2;
  unsigned short* R = (b < 64) ? R1 : R2;
  int e  = ((b & 63) * 256 + (int)threadIdx.x) * 4;  // [0, 65536)
  int n  = e >> 8;
  int k0 = e & 255;
  u16x4 h;
  #pragma unroll
  for (int i = 0; i < 4; ++i) h[i] = f2bf(W[(k0 + i) * 256 + n]);
  int kt = k0 >> 6, kl = k0 & 63;
  int off = kt * 16384 + n * 64 + (((kl >> 3) ^ (n & 7)) << 3) + (kl & 7);
  *(u16x4*)(R + off) = h;
}

// ---------------------------------------------------------------------------
// Fused: out[128 x 256] = relu(X[128 x 256] @ W1 + b1) @ W2 + b2, one block
// per 128-row tile. 512 threads = 8 waves (2M x 4N); wave tile 64x64 as 4x4
// frags of 16x16x32 bf16.
// LDS (128 KB): Hbuf 64KB (aliases Ab0/Ab1 X-staging dbuf 2x16KB) + W dbuf
// 2x32KB. H never touches HBM. W2 kt0 prefetched during GEMM1 kt3.
// ---------------------------------------------------------------------------
__global__ __launch_bounds__(512, 2)
void cheb_fused(const float* __restrict__ X,
                const unsigned short* __restrict__ W1img,
                const unsigned short* __restrict__ W2img,
                const float* __restrict__ b1,
                const float* __restrict__ b2,
                float* __restrict__ out)
{
  __shared__ unsigned short lds[65536];   // 128 KB
  unsigned short* Hbuf = lds;             // 32768 ushorts (64 KB) = Ab0+Ab1+32KB
  unsigned short* Ab0  = lds;             // 8192 ushorts (16 KB)
  unsigned short* Ab1  = lds + 8192;
  unsigned short* Wb0  = lds + 32768;     // 16384 ushorts (32 KB)
  unsigned short* Wb1  = lds + 49152;

  const int tid  = threadIdx.x;
  const int lane = tid & 63;
  const int w    = tid >> 6;              // 0..7
  const int wr   = w >> 2;                // 0..1 (row half)
  const int wc   = w & 3;                 // 0..3 (col quarter)
  const int rb   = blockIdx.x;

  f32x4 acc[4][4] = {};
  f32x4 areg[4];

  auto stageW = [&](const unsigned short* img, int kt, unsigned short* dst) {
    const unsigned short* src = img + kt * 16384;
    #pragma unroll
    for (int it = 0; it < 4; ++it) {
      int chunk = it * 8 + w;             // wave-uniform; 32 chunks x 1KB
      __builtin_amdgcn_global_load_lds(
          (const __attribute__((address_space(1))) unsigned int*)(const void*)(src + chunk * 512 + lane * 8),
          (__attribute__((address_space(3))) unsigned int*)(void*)(dst + chunk * 512),
          16, 0, 0);
    }
  };
  auto loadA = [&](int kt) {              // X f32 -> regs (latency under compute)
    #pragma unroll
    for (int i = 0; i < 4; ++i) {
      int e = (i * 512 + tid) * 4;        // [0, 8192): 128 rows x 64 cols
      int r = e >> 6, c = e & 63;
      int grow = rb * BM + r;
      f32x4 v = {0.f, 0.f, 0.f, 0.f};
      if (grow < M_NODES) v = *(const f32x4*)(X + (size_t)grow * 256 + kt * 64 + c);
      areg[i] = v;
    }
  };
  auto writeA = [&](unsigned short* dst) {  // cvt + swizzled ds_write
    #pragma unroll
    for (int i = 0; i < 4; ++i) {
      int e = (i * 512 + tid) * 4;
      int r = e >> 6, c = e & 63;
      u16x4 h;
      #pragma unroll
      for (int j = 0; j < 4; ++j) h[j] = f2bf(areg[i][j]);
      int off = r * 64 + (((c >> 3) ^ (r & 7)) << 3) + (c & 7);
      *(u16x4*)(dst + off) = h;
    }
  };
  // A frags from (Abase, row stride rstride ushorts, k-slot base), B from Wbuf
  auto compute = [&](const unsigned short* Abase, int rstride, int slotbase,
                     const unsigned short* B) {
    #pragma unroll
    for (int kk = 0; kk < 2; ++kk) {
      bf16x8 a[4], b[4];
      #pragma unroll
      for (int mi = 0; mi < 4; ++mi) {
        int r = wr * 64 + mi * 16 + (lane & 15);
        int slot = (slotbase + kk * 4 + (lane >> 4)) ^ (r & 7);
        a[mi] = *(const bf16x8*)(Abase + r * rstride + slot * 8);
      }
      #pragma unroll
      for (int ni = 0; ni < 4; ++ni) {
        int n = wc * 64 + ni * 16 + (lane & 15);
        int slot = (kk * 4 + (lane >> 4)) ^ (n & 7);
        b[ni] = *(const bf16x8*)(B + n * 64 + slot * 8);
      }
      #pragma unroll
      for (int mi = 0; mi < 4; ++mi)
        #pragma unroll
        for (int ni = 0; ni < 4; ++ni)
          acc[mi][ni] = __builtin_amdgcn_mfma_f32_16x16x32_bf16(a[mi], b[ni], acc[mi][ni], 0, 0, 0);
    }
  };

  // ---- GEMM1: H = relu(X @ W1 + b1) --------------------------------------
  loadA(0);
  stageW(W1img, 0, Wb0);
  writeA(Ab0);
  __syncthreads();

  #pragma unroll
  for (int kt = 0; kt < 4; ++kt) {
    unsigned short* Acur = (kt & 1) ? Ab1 : Ab0;
    unsigned short* Anxt = (kt & 1) ? Ab0 : Ab1;
    unsigned short* Wcur = (kt & 1) ? Wb1 : Wb0;
    unsigned short* Wnxt = (kt & 1) ? Wb0 : Wb1;
    if (kt < 3) {
      loadA(kt + 1);
      stageW(W1img, kt + 1, Wnxt);
    } else {
      stageW(W2img, 0, Wnxt);             // prefetch GEMM2 kt0 into Wb0
    }
    compute(Acur, 64, 0, Wcur);
    if (kt < 3) writeA(Anxt);
    __syncthreads();
  }

  // ---- epilogue1: acc -> Hbuf (bias + relu + bf16, swizzled) -------------
  {
    float bn[4];
    #pragma unroll
    for (int ni = 0; ni < 4; ++ni) bn[ni] = b1[wc * 64 + ni * 16 + (lane & 15)];
    #pragma unroll
    for (int mi = 0; mi < 4; ++mi)
      #pragma unroll
      for (int ni = 0; ni < 4; ++ni) {
        int k = wc * 64 + ni * 16 + (lane & 15);
        #pragma unroll
        for (int rg = 0; rg < 4; ++rg) {
          int r = wr * 64 + mi * 16 + (lane >> 4) * 4 + rg;
          float v = fmaxf(acc[mi][ni][rg] + bn[ni], 0.f);
          int off = r * 256 + (((k >> 3) ^ (r & 7)) << 3) + (k & 7);
          Hbuf[off] = f2bf(v);
          acc[mi][ni][rg] = 0.f;          // reset for GEMM2
        }
      }
  }
  __syncthreads();                        // Hbuf visible to all waves

  // ---- GEMM2: out = H @ W2 + b2 ------------------------------------------
  #pragma unroll
  for (int kt = 0; kt < 4; ++kt) {
    unsigned short* Wcur = (kt & 1) ? Wb1 : Wb0;
    unsigned short* Wnxt = (kt & 1) ? Wb0 : Wb1;
    if (kt < 3) stageW(W2img, kt + 1, Wnxt);
    compute(Hbuf, 256, kt * 8, Wcur);
    if (kt < 3) __syncthreads();
  }

  // ---- epilogue2: store f32 ----------------------------------------------
  {
    float bn[4];
    #pragma unroll
    for (int ni = 0; ni < 4; ++ni) bn[ni] = b2[wc * 64 + ni * 16 + (lane & 15)];
    #pragma unroll
    for (int mi = 0; mi < 4; ++mi)
      #pragma unroll
      for (int rg = 0; rg < 4; ++rg) {
        int r = wr * 64 + mi * 16 + (lane >> 4) * 4 + rg;
        int grow = rb * BM + r;
        if (grow < M_NODES) {
          #pragma unroll
          for (int ni = 0; ni < 4; ++ni) {
            int col = wc * 64 + ni * 16 + (lane & 15);
            out[(size_t)grow * 256 + col] = acc[mi][ni][rg] + bn[ni];
          }
        }
      }
  }
}

// ---------------------------------------------------------------------------
extern "C" void kernel_launch(void* const* d_in, const int* in_sizes, int n_in,
                              void* d_out, int out_size, void* d_ws, size_t ws_size,
                              hipStream_t stream) {
  const float* emb = (const float*)d_in[0];
  const float* W1  = (const float*)d_in[1];
  const float* b1  = (const float*)d_in[2];
  const float* W2  = (const float*)d_in[3];
  const float* b2  = (const float*)d_in[4];
  // d_in[5] = prop_edge_index: unused at ChebConv K=1.
  float* out = (float*)d_out;

  unsigned short* Wr1 = (unsigned short*)d_ws;   // 65536 ushorts (128KB)
  unsigned short* Wr2 = Wr1 + 65536;             // 128KB

  prep_w_kernel<<<128, 256, 0, stream>>>(W1, W2, Wr1, Wr2);
  cheb_fused<<<NBLK, 512, 0, stream>>>(emb, Wr1, Wr2, b1, b2, out);
}